// Round 6
// baseline (111.962 us; speedup 1.0000x reference)
//
#include <hip/hip_runtime.h>
#include <math.h>

#define N_SPK 512
#define N_UTT 32
#define DIM   512
#define EPSN  1e-8f

typedef __attribute__((ext_vector_type(8))) short  short8;  // 8 bf16 = 4 VGPR
typedef __attribute__((ext_vector_type(4))) float  f32x4;   // MFMA C/D

// fp32 -> bf16 round-to-nearest-even
__device__ inline unsigned short f2bf(float x) {
  unsigned int u = __builtin_bit_cast(unsigned int, x);
  unsigned int r = (u + 0x7fffu + ((u >> 16) & 1u)) >> 16;
  return (unsigned short)r;
}

// ws layout:
//   [0, 512KB)          cnk  — normalized centroids, bf16, K-chunked:
//                               cnk[(kc*N_SPK+c)*32 + (k&31)], kc = k/32
//   [512KB, 512KB+16MB) Eg   — normalized rows, bf16, PRE-SWIZZLED in 16B
//                               chunks (chunk c of row r at c ^ (r&7))
//   then partials[512] (2KB), then 4B done-counter
#define CNK_BYTES ((size_t)N_SPK * DIM * 2)
#define EG_BYTES  ((size_t)N_SPK * N_UTT * DIM * 2)

// Kernel 1 (prep): block j reads speaker j's 64KB ONCE. Produces:
//  - row-normalized bf16 rows -> Eg (pre-swizzled, so ge2e's LDS copy is a
//    straight memcpy and its A-frag reads stay conflict-free)
//  - column means -> L2-normalized centroid -> cnk (K-chunked, coalesced)
// Also zeroes the done-counter for ge2e's fused finalize (stream-ordered).
__global__ __launch_bounds__(512) void prep_kernel(
    const float* __restrict__ emb, unsigned short* __restrict__ cnk,
    unsigned short* __restrict__ Eg, unsigned int* __restrict__ counter) {
  __shared__ float colsum[8][DIM];  // 16 KB
  __shared__ float nred[8];
  int j = blockIdx.x, t = threadIdx.x;
  int lane = t & 63, wid = t >> 6;
  if (j == 0 && t == 0) *counter = 0;

  float cs[8];
#pragma unroll
  for (int i = 0; i < 8; ++i) cs[i] = 0.f;

  // wave wid owns rows wid*4..wid*4+3; lane covers cols lane*8..lane*8+7
#pragma unroll
  for (int r8 = 0; r8 < 4; ++r8) {
    int r = wid * 4 + r8;
    const float* rp = emb + ((size_t)j * N_UTT + r) * DIM + lane * 8;
    float4 v0 = *(const float4*)rp;
    float4 v1 = *(const float4*)(rp + 4);
    cs[0] += v0.x; cs[1] += v0.y; cs[2] += v0.z; cs[3] += v0.w;
    cs[4] += v1.x; cs[5] += v1.y; cs[6] += v1.z; cs[7] += v1.w;
    float ss = v0.x * v0.x + v0.y * v0.y + v0.z * v0.z + v0.w * v0.w +
               v1.x * v1.x + v1.y * v1.y + v1.z * v1.z + v1.w * v1.w;
#pragma unroll
    for (int off = 32; off > 0; off >>= 1) ss += __shfl_xor(ss, off, 64);
    float inv = 1.f / fmaxf(sqrtf(ss), EPSN);
    short8 pk;
    pk[0] = (short)f2bf(v0.x * inv); pk[1] = (short)f2bf(v0.y * inv);
    pk[2] = (short)f2bf(v0.z * inv); pk[3] = (short)f2bf(v0.w * inv);
    pk[4] = (short)f2bf(v1.x * inv); pk[5] = (short)f2bf(v1.y * inv);
    pk[6] = (short)f2bf(v1.z * inv); pk[7] = (short)f2bf(v1.w * inv);
    int sw = lane ^ (r & 7);  // pre-swizzle: 16B chunk XOR
    *(short8*)&Eg[((size_t)j * N_UTT + r) * DIM + sw * 8] = pk;
  }
  *(float4*)&colsum[wid][lane * 8] = (float4){cs[0], cs[1], cs[2], cs[3]};
  *(float4*)&colsum[wid][lane * 8 + 4] = (float4){cs[4], cs[5], cs[6], cs[7]};
  __syncthreads();

  // centroid: thread t owns column t
  float c = 0.f;
#pragma unroll
  for (int ww = 0; ww < 8; ++ww) c += colsum[ww][t];
  c *= (1.f / N_UTT);
  float ss = c * c;
#pragma unroll
  for (int off = 32; off > 0; off >>= 1) ss += __shfl_xor(ss, off, 64);
  if (lane == 0) nred[wid] = ss;
  __syncthreads();
  float total = nred[0] + nred[1] + nred[2] + nred[3] +
                nred[4] + nred[5] + nred[6] + nred[7];
  float cinv = 1.f / fmaxf(sqrtf(total), EPSN);
  cnk[((size_t)(t >> 5) * N_SPK + j) * 32 + (t & 31)] = f2bf(c * cinv);
}

// Kernel 2: block j = speaker j, 512 threads (8 waves; wave owns 64 cols).
// Proven R3 GEMM shape (VGPR 76 < 128 cap — no spills). Phase 1 is now a
// straight 32KB global->LDS copy of pre-normalized bf16 rows. Fused
// last-block finalize (no 3rd launch).
__global__ __launch_bounds__(512, 4) void ge2e_kernel(
    const unsigned short* __restrict__ Eg,
    const unsigned short* __restrict__ cnk,
    const float* __restrict__ wp, const float* __restrict__ bp,
    float* __restrict__ partials, unsigned int* __restrict__ counter,
    float* __restrict__ out) {
  __shared__ __align__(16) unsigned short E[N_UTT * DIM];  // 32 KB
  __shared__ float red[8][N_UTT][2];                       // 2 KB (m, s)
  __shared__ float dred[8];
  __shared__ float nred[8];
  __shared__ int amLast;

  int j = blockIdx.x;
  int t = threadIdx.x;
  int lane = t & 63, wid = t >> 6;
  int n15 = lane & 15, quad = lane >> 4;

  // ---- stage: straight copy, layout already swizzled ----
  const int4* src = (const int4*)(Eg + (size_t)j * N_UTT * DIM);
  int4* dst = (int4*)E;
#pragma unroll
  for (int i = 0; i < 4; ++i) dst[i * 512 + t] = src[i * 512 + t];
  __syncthreads();

  // ---- MFMA GEMM: wave wid computes rows 0..31 x cols wid*64..+63 ----
  f32x4 acc[2][4];
#pragma unroll
  for (int mt = 0; mt < 2; ++mt)
#pragma unroll
    for (int nt = 0; nt < 4; ++nt) acc[mt][nt] = (f32x4){0.f, 0.f, 0.f, 0.f};

  for (int ks = 0; ks < 16; ++ks) {
    short8 b[4];
#pragma unroll
    for (int nt = 0; nt < 4; ++nt) {
      int c = wid * 64 + nt * 16 + n15;  // B[n][k]: contiguous 1KB per run
      b[nt] = *(const short8*)(cnk + ((size_t)ks * N_SPK + c) * 32 + quad * 8);
    }
    short8 a[2];
#pragma unroll
    for (int mt = 0; mt < 2; ++mt) {
      int r = mt * 16 + n15;
      int sw = (ks * 4 + quad) ^ (r & 7);
      a[mt] = *(const short8*)&E[r * DIM + sw * 8];
    }
#pragma unroll
    for (int mt = 0; mt < 2; ++mt)
#pragma unroll
      for (int nt = 0; nt < 4; ++nt)
        acc[mt][nt] = __builtin_amdgcn_mfma_f32_16x16x32_bf16(
            a[mt], b[nt], acc[mt][nt], 0, 0, 0);
  }

  // ---- epilogue: logits = w*sim+b, fused LSE + diag ----
  float w = *wp, bb = *bp;
  float dsum = 0.f;
#pragma unroll
  for (int mt = 0; mt < 2; ++mt)
#pragma unroll
    for (int nt = 0; nt < 4; ++nt) {
      int c = wid * 64 + nt * 16 + n15;
      bool isdiag = (c == j);
#pragma unroll
      for (int rg = 0; rg < 4; ++rg) {
        float v = fmaf(w, acc[mt][nt][rg], bb);
        acc[mt][nt][rg] = v;
        if (isdiag) dsum += v;
      }
    }

#pragma unroll
  for (int mt = 0; mt < 2; ++mt)
#pragma unroll
    for (int rg = 0; rg < 4; ++rg) {
      float m = -INFINITY;
#pragma unroll
      for (int nt = 0; nt < 4; ++nt) m = fmaxf(m, acc[mt][nt][rg]);
#pragma unroll
      for (int off = 1; off < 16; off <<= 1) m = fmaxf(m, __shfl_xor(m, off, 64));
      float s = 0.f;
#pragma unroll
      for (int nt = 0; nt < 4; ++nt) s += __expf(acc[mt][nt][rg] - m);
#pragma unroll
      for (int off = 1; off < 16; off <<= 1) s += __shfl_xor(s, off, 64);
      if (n15 == 0) {
        int r = mt * 16 + quad * 4 + rg;
        red[wid][r][0] = m;
        red[wid][r][1] = s;
      }
    }
#pragma unroll
  for (int off = 32; off > 0; off >>= 1) dsum += __shfl_xor(dsum, off, 64);
  if (lane == 0) dred[wid] = dsum;
  __syncthreads();

  // combine 8 wave-partials per row; rows 0..31 on threads 0..31
  if (t < 32) {
    float M = -INFINITY;
#pragma unroll
    for (int ww = 0; ww < 8; ++ww) M = fmaxf(M, red[ww][t][0]);
    float S = 0.f;
#pragma unroll
    for (int ww = 0; ww < 8; ++ww) S += red[ww][t][1] * __expf(red[ww][t][0] - M);
    float lse = M + __logf(S);
#pragma unroll
    for (int off = 16; off > 0; off >>= 1) lse += __shfl_xor(lse, off, 64);
    if (t == 0) {
      float d = dred[0] + dred[1] + dred[2] + dred[3] +
                dred[4] + dred[5] + dred[6] + dred[7];
      partials[j] = lse - d;
    }
  }

  // ---- fused finalize: last block to arrive reduces the 512 partials ----
  if (t == 0) {
    __threadfence();                       // release partials[j] device-wide
    unsigned int old = atomicAdd(counter, 1u);
    amLast = (old == (unsigned int)(gridDim.x - 1));
  }
  __syncthreads();
  if (amLast) {
    __threadfence();                       // acquire all partials
    float v = partials[t];                 // 512 threads == N_SPK
#pragma unroll
    for (int off = 32; off > 0; off >>= 1) v += __shfl_xor(v, off, 64);
    if (lane == 0) nred[wid] = v;
    __syncthreads();
    if (t == 0) {
      float s = nred[0] + nred[1] + nred[2] + nred[3] +
                nred[4] + nred[5] + nred[6] + nred[7];
      out[0] = s * (1.f / (N_SPK * N_UTT));
    }
  }
}

extern "C" void kernel_launch(void* const* d_in, const int* in_sizes, int n_in,
                              void* d_out, int out_size, void* d_ws, size_t ws_size,
                              hipStream_t stream) {
  const float* emb = (const float*)d_in[0];
  const float* wp  = (const float*)d_in[1];
  const float* bp  = (const float*)d_in[2];
  float* out = (float*)d_out;
  unsigned short* cnk = (unsigned short*)d_ws;
  unsigned short* Eg  = (unsigned short*)((char*)d_ws + CNK_BYTES);
  float* partials = (float*)((char*)d_ws + CNK_BYTES + EG_BYTES);
  unsigned int* counter =
      (unsigned int*)((char*)d_ws + CNK_BYTES + EG_BYTES + N_SPK * 4);

  prep_kernel<<<N_SPK, 512, 0, stream>>>(emb, cnk, Eg, counter);
  ge2e_kernel<<<N_SPK, 512, 0, stream>>>(Eg, cnk, wp, bp, partials, counter,
                                         out);
}

// Round 7
// 104.372 us; speedup vs baseline: 1.0727x; 1.0727x over previous
//
#include <hip/hip_runtime.h>
#include <math.h>

#define N_SPK 512
#define N_UTT 32
#define DIM   512
#define EPSN  1e-8f

typedef __attribute__((ext_vector_type(8))) short  short8;  // 8 bf16 = 4 VGPR
typedef __attribute__((ext_vector_type(4))) float  f32x4;   // MFMA C/D

// fp32 -> bf16 round-to-nearest-even
__device__ inline unsigned short f2bf(float x) {
  unsigned int u = __builtin_bit_cast(unsigned int, x);
  unsigned int r = (u + 0x7fffu + ((u >> 16) & 1u)) >> 16;
  return (unsigned short)r;
}

// ws layout:
//   [0, 512KB)          cnk  — normalized centroids, bf16, K-chunked:
//                               cnk[(kc*N_SPK+c)*32 + (k&31)], kc = k/32
//   [512KB, 512KB+16MB) Eg   — normalized rows, bf16, PRE-SWIZZLED in 16B
//                               chunks (chunk c of row r at c ^ (r&7))
//   then partials[512] (2KB)
#define CNK_BYTES ((size_t)N_SPK * DIM * 2)
#define EG_BYTES  ((size_t)N_SPK * N_UTT * DIM * 2)

// Kernel 1 (prep): block j reads speaker j's 64KB ONCE. Produces:
//  - row-normalized bf16 rows -> Eg (pre-swizzled: ge2e's LDS copy is a
//    straight memcpy, A-frag reads stay conflict-free)
//  - column means -> L2-normalized centroid -> cnk (K-chunked, coalesced)
// NO fences, NO counter — kernel boundary provides coherence (R5/R6's
// in-kernel device fences cost ~10-15us in L2 writebacks).
__global__ __launch_bounds__(512) void prep_kernel(
    const float* __restrict__ emb, unsigned short* __restrict__ cnk,
    unsigned short* __restrict__ Eg) {
  __shared__ float colsum[8][DIM];  // 16 KB
  __shared__ float nred[8];
  int j = blockIdx.x, t = threadIdx.x;
  int lane = t & 63, wid = t >> 6;

  float cs[8];
#pragma unroll
  for (int i = 0; i < 8; ++i) cs[i] = 0.f;

  // wave wid owns rows wid*4..wid*4+3; lane covers cols lane*8..lane*8+7
#pragma unroll
  for (int r8 = 0; r8 < 4; ++r8) {
    int r = wid * 4 + r8;
    const float* rp = emb + ((size_t)j * N_UTT + r) * DIM + lane * 8;
    float4 v0 = *(const float4*)rp;
    float4 v1 = *(const float4*)(rp + 4);
    cs[0] += v0.x; cs[1] += v0.y; cs[2] += v0.z; cs[3] += v0.w;
    cs[4] += v1.x; cs[5] += v1.y; cs[6] += v1.z; cs[7] += v1.w;
    float ss = v0.x * v0.x + v0.y * v0.y + v0.z * v0.z + v0.w * v0.w +
               v1.x * v1.x + v1.y * v1.y + v1.z * v1.z + v1.w * v1.w;
#pragma unroll
    for (int off = 32; off > 0; off >>= 1) ss += __shfl_xor(ss, off, 64);
    float inv = 1.f / fmaxf(sqrtf(ss), EPSN);
    short8 pk;
    pk[0] = (short)f2bf(v0.x * inv); pk[1] = (short)f2bf(v0.y * inv);
    pk[2] = (short)f2bf(v0.z * inv); pk[3] = (short)f2bf(v0.w * inv);
    pk[4] = (short)f2bf(v1.x * inv); pk[5] = (short)f2bf(v1.y * inv);
    pk[6] = (short)f2bf(v1.z * inv); pk[7] = (short)f2bf(v1.w * inv);
    int sw = lane ^ (r & 7);  // pre-swizzle: 16B chunk XOR
    *(short8*)&Eg[((size_t)j * N_UTT + r) * DIM + sw * 8] = pk;
  }
  *(float4*)&colsum[wid][lane * 8] = (float4){cs[0], cs[1], cs[2], cs[3]};
  *(float4*)&colsum[wid][lane * 8 + 4] = (float4){cs[4], cs[5], cs[6], cs[7]};
  __syncthreads();

  // centroid: thread t owns column t
  float c = 0.f;
#pragma unroll
  for (int ww = 0; ww < 8; ++ww) c += colsum[ww][t];
  c *= (1.f / N_UTT);
  float ss = c * c;
#pragma unroll
  for (int off = 32; off > 0; off >>= 1) ss += __shfl_xor(ss, off, 64);
  if (lane == 0) nred[wid] = ss;
  __syncthreads();
  float total = nred[0] + nred[1] + nred[2] + nred[3] +
                nred[4] + nred[5] + nred[6] + nred[7];
  float cinv = 1.f / fmaxf(sqrtf(total), EPSN);
  cnk[((size_t)(t >> 5) * N_SPK + j) * 32 + (t & 31)] = f2bf(c * cinv);
}

// Kernel 2: block j = speaker j, 512 threads (8 waves; wave owns 64 cols).
// Proven R3 GEMM shape (VGPR 76 — no spills). Phase 1 is a straight 32KB
// global->LDS copy of pre-normalized bf16 rows. Plain partials[] store —
// separate finalize kernel (kernel-boundary coherence, no fences).
__global__ __launch_bounds__(512, 4) void ge2e_kernel(
    const unsigned short* __restrict__ Eg,
    const unsigned short* __restrict__ cnk,
    const float* __restrict__ wp, const float* __restrict__ bp,
    float* __restrict__ partials) {
  __shared__ __align__(16) unsigned short E[N_UTT * DIM];  // 32 KB
  __shared__ float red[8][N_UTT][2];                       // 2 KB (m, s)
  __shared__ float dred[8];

  int j = blockIdx.x;
  int t = threadIdx.x;
  int lane = t & 63, wid = t >> 6;
  int n15 = lane & 15, quad = lane >> 4;

  // ---- stage: straight copy, layout already swizzled ----
  const int4* src = (const int4*)(Eg + (size_t)j * N_UTT * DIM);
  int4* dst = (int4*)E;
#pragma unroll
  for (int i = 0; i < 4; ++i) dst[i * 512 + t] = src[i * 512 + t];
  __syncthreads();

  // ---- MFMA GEMM: wave wid computes rows 0..31 x cols wid*64..+63 ----
  f32x4 acc[2][4];
#pragma unroll
  for (int mt = 0; mt < 2; ++mt)
#pragma unroll
    for (int nt = 0; nt < 4; ++nt) acc[mt][nt] = (f32x4){0.f, 0.f, 0.f, 0.f};

  for (int ks = 0; ks < 16; ++ks) {
    short8 b[4];
#pragma unroll
    for (int nt = 0; nt < 4; ++nt) {
      int c = wid * 64 + nt * 16 + n15;  // B[n][k]: contiguous 1KB per run
      b[nt] = *(const short8*)(cnk + ((size_t)ks * N_SPK + c) * 32 + quad * 8);
    }
    short8 a[2];
#pragma unroll
    for (int mt = 0; mt < 2; ++mt) {
      int r = mt * 16 + n15;
      int sw = (ks * 4 + quad) ^ (r & 7);
      a[mt] = *(const short8*)&E[r * DIM + sw * 8];
    }
#pragma unroll
    for (int mt = 0; mt < 2; ++mt)
#pragma unroll
      for (int nt = 0; nt < 4; ++nt)
        acc[mt][nt] = __builtin_amdgcn_mfma_f32_16x16x32_bf16(
            a[mt], b[nt], acc[mt][nt], 0, 0, 0);
  }

  // ---- epilogue: logits = w*sim+b, fused LSE + diag ----
  float w = *wp, bb = *bp;
  float dsum = 0.f;
#pragma unroll
  for (int mt = 0; mt < 2; ++mt)
#pragma unroll
    for (int nt = 0; nt < 4; ++nt) {
      int c = wid * 64 + nt * 16 + n15;
      bool isdiag = (c == j);
#pragma unroll
      for (int rg = 0; rg < 4; ++rg) {
        float v = fmaf(w, acc[mt][nt][rg], bb);
        acc[mt][nt][rg] = v;
        if (isdiag) dsum += v;
      }
    }

#pragma unroll
  for (int mt = 0; mt < 2; ++mt)
#pragma unroll
    for (int rg = 0; rg < 4; ++rg) {
      float m = -INFINITY;
#pragma unroll
      for (int nt = 0; nt < 4; ++nt) m = fmaxf(m, acc[mt][nt][rg]);
#pragma unroll
      for (int off = 1; off < 16; off <<= 1) m = fmaxf(m, __shfl_xor(m, off, 64));
      float s = 0.f;
#pragma unroll
      for (int nt = 0; nt < 4; ++nt) s += __expf(acc[mt][nt][rg] - m);
#pragma unroll
      for (int off = 1; off < 16; off <<= 1) s += __shfl_xor(s, off, 64);
      if (n15 == 0) {
        int r = mt * 16 + quad * 4 + rg;
        red[wid][r][0] = m;
        red[wid][r][1] = s;
      }
    }
#pragma unroll
  for (int off = 32; off > 0; off >>= 1) dsum += __shfl_xor(dsum, off, 64);
  if (lane == 0) dred[wid] = dsum;
  __syncthreads();

  // combine 8 wave-partials per row; rows 0..31 on threads 0..31
  if (t < 32) {
    float M = -INFINITY;
#pragma unroll
    for (int ww = 0; ww < 8; ++ww) M = fmaxf(M, red[ww][t][0]);
    float S = 0.f;
#pragma unroll
    for (int ww = 0; ww < 8; ++ww) S += red[ww][t][1] * __expf(red[ww][t][0] - M);
    float lse = M + __logf(S);
#pragma unroll
    for (int off = 16; off > 0; off >>= 1) lse += __shfl_xor(lse, off, 64);
    if (t == 0) {
      float d = dred[0] + dred[1] + dred[2] + dred[3] +
                dred[4] + dred[5] + dred[6] + dred[7];
      partials[j] = lse - d;  // plain store; kernel boundary = coherence
    }
  }
}

// Kernel 3: reduce the 512 per-block partials -> the loss scalar.
__global__ __launch_bounds__(512) void finalize_kernel(
    const float* __restrict__ partials, float* __restrict__ out) {
  int t = threadIdx.x;
  float v = partials[t];
#pragma unroll
  for (int off = 32; off > 0; off >>= 1) v += __shfl_xor(v, off, 64);
  __shared__ float r[8];
  if ((t & 63) == 0) r[t >> 6] = v;
  __syncthreads();
  if (t == 0) {
    float s = r[0] + r[1] + r[2] + r[3] + r[4] + r[5] + r[6] + r[7];
    out[0] = s * (1.f / (N_SPK * N_UTT));
  }
}

extern "C" void kernel_launch(void* const* d_in, const int* in_sizes, int n_in,
                              void* d_out, int out_size, void* d_ws, size_t ws_size,
                              hipStream_t stream) {
  const float* emb = (const float*)d_in[0];
  const float* wp  = (const float*)d_in[1];
  const float* bp  = (const float*)d_in[2];
  float* out = (float*)d_out;
  unsigned short* cnk = (unsigned short*)d_ws;
  unsigned short* Eg  = (unsigned short*)((char*)d_ws + CNK_BYTES);
  float* partials = (float*)((char*)d_ws + CNK_BYTES + EG_BYTES);

  prep_kernel<<<N_SPK, 512, 0, stream>>>(emb, cnk, Eg);
  ge2e_kernel<<<N_SPK, 512, 0, stream>>>(Eg, cnk, wp, bp, partials);
  finalize_kernel<<<1, 512, 0, stream>>>(partials, out);
}